// Round 1
// baseline (609.253 us; speedup 1.0000x reference)
//
#include <hip/hip_runtime.h>
#include <cstdint>
#include <cstddef>

#define TSTEPS 8
#define D 64

// ---------------------------------------------------------------------------
// Phase A: build CSR over dst (counts -> exclusive scan -> bucket fill)
// ---------------------------------------------------------------------------
__global__ void hist_kernel(const int* __restrict__ dst, int E, int* __restrict__ cnt) {
    int e = blockIdx.x * blockDim.x + threadIdx.x;
    if (e < E) atomicAdd(&cnt[dst[e]], 1);
}

__global__ __launch_bounds__(1024) void scan_kernel(const int* __restrict__ cnt,
                                                    int* __restrict__ rowptr,
                                                    int* __restrict__ fill, int n) {
    __shared__ int buf[1024];
    __shared__ int carry_s;
    int tid = threadIdx.x;
    if (tid == 0) carry_s = 0;
    __syncthreads();
    for (int base = 0; base < n; base += 1024) {
        int i = base + tid;
        int v = (i < n) ? cnt[i] : 0;
        buf[tid] = v;
        __syncthreads();
        // Hillis-Steele inclusive scan (double barrier)
        for (int off = 1; off < 1024; off <<= 1) {
            int t = (tid >= off) ? buf[tid - off] : 0;
            __syncthreads();
            buf[tid] += t;
            __syncthreads();
        }
        int carry = carry_s;
        int excl = carry + buf[tid] - v;
        if (i < n) { rowptr[i] = excl; fill[i] = excl; }
        __syncthreads();
        if (tid == 1023) carry_s = carry + buf[1023];
        __syncthreads();
    }
    if (tid == 0) rowptr[n] = carry_s;
}

__global__ void bucket_kernel(const int* __restrict__ dst, int E,
                              int* __restrict__ fill, int* __restrict__ bucket) {
    int e = blockIdx.x * blockDim.x + threadIdx.x;
    if (e < E) {
        int p = atomicAdd(&fill[dst[e]], 1);
        bucket[p] = e;
    }
}

// ---------------------------------------------------------------------------
// Phase B: per-node gather. One wave per dst node; lane = feature dim.
// acc[t][lane] = sum over edges with t >= t0(edge) of x[t, src, lane] * w.
// Writes the raw aggregate into d_out (linear applied afterwards, in-place).
// ---------------------------------------------------------------------------
__global__ __launch_bounds__(256) void gather_kernel(
    const float* __restrict__ x, const int* __restrict__ src,
    const float* __restrict__ etime, const float* __restrict__ ew,
    const float* __restrict__ ntime, const int* __restrict__ rowptr,
    const int* __restrict__ bucket, float* __restrict__ out, int N)
{
    int wid  = (int)((blockIdx.x * blockDim.x + threadIdx.x) >> 6);
    int lane = threadIdx.x & 63;
    if (wid >= N) return;

    float nt[TSTEPS];
#pragma unroll
    for (int t = 0; t < TSTEPS; t++) nt[t] = ntime[t];

    int p0 = rowptr[wid], p1 = rowptr[wid + 1];
    float acc[TSTEPS];
#pragma unroll
    for (int t = 0; t < TSTEPS; t++) acc[t] = 0.f;

    const size_t plane = (size_t)N * D;

    for (int p = p0; p < p1; p += 64) {
        int idx = p + lane;
        int sv = 0, t0v = TSTEPS;
        float wv = 0.f;
        if (idx < p1) {
            int e = bucket[idx];
            sv = src[e];
            float et = etime[e];
            wv = ew[e];
            int t0 = 0;
#pragma unroll
            for (int t = 0; t < TSTEPS; t++) t0 += (nt[t] < et) ? 1 : 0;
            t0v = t0;   // active for t in [t0, TSTEPS)
        }
        int cnt = p1 - p; if (cnt > 64) cnt = 64;
        for (int i = 0; i < cnt; ++i) {
            int   si = __builtin_amdgcn_readlane(sv, i);
            int   ti = __builtin_amdgcn_readlane(t0v, i);
            float wi = __int_as_float(__builtin_amdgcn_readlane(__float_as_int(wv), i));
            const float* xp = x + (size_t)si * D + lane;
#pragma unroll
            for (int t = 0; t < TSTEPS; t++) {
                if (t >= ti)   // scalar (uniform) branch -> inactive t loads skipped
                    acc[t] = fmaf(xp[(size_t)t * plane], wi, acc[t]);
            }
        }
    }

    size_t o = (size_t)wid * D + lane;
#pragma unroll
    for (int t = 0; t < TSTEPS; t++) out[(size_t)t * plane + o] = acc[t];
}

// ---------------------------------------------------------------------------
// Phase C: in-place row-wise linear: row <- row @ W + b.
// Block = 256 threads, 128 rows/block, each thread: 8 rows x 4 cols.
// W staged in LDS (16 KB); x rows staged with stride 65 (conflict-free).
// ---------------------------------------------------------------------------
#define RPB 128   // rows per block
__global__ __launch_bounds__(256) void transform_kernel(
    float* __restrict__ out, const float* __restrict__ W,
    const float* __restrict__ b, int totalRows)
{
    __shared__ float xs[RPB * 65];
    __shared__ float Ws[64 * 64];
    int tid = threadIdx.x;

#pragma unroll
    for (int i = 0; i < 16; i++) Ws[tid + i * 256] = W[tid + i * 256];

    long rbase = (long)blockIdx.x * RPB;
    const float4* gin = (const float4*)(out + (size_t)rbase * D);
#pragma unroll
    for (int i = 0; i < 8; i++) {
        int fi = tid + i * 256;            // float4 index within block tile
        int fl = fi * 4;
        int r = fl >> 6, c = fl & 63;
        if (rbase + r < totalRows) {
            float4 v = gin[fi];
            float* dsto = &xs[r * 65 + c];
            dsto[0] = v.x; dsto[1] = v.y; dsto[2] = v.z; dsto[3] = v.w;
        }
    }
    __syncthreads();

    int jg = tid & 15;    // col group: cols 4*jg .. 4*jg+3
    int rb = tid >> 4;    // row group: rows rb*8 .. rb*8+7

    float acc[8][4];
#pragma unroll
    for (int rr = 0; rr < 8; rr++)
#pragma unroll
        for (int c = 0; c < 4; c++) acc[rr][c] = 0.f;

    for (int k = 0; k < 64; k++) {
        float4 wv = *(const float4*)&Ws[k * 64 + 4 * jg];
#pragma unroll
        for (int rr = 0; rr < 8; rr++) {
            float xv = xs[(rb * 8 + rr) * 65 + k];
            acc[rr][0] = fmaf(xv, wv.x, acc[rr][0]);
            acc[rr][1] = fmaf(xv, wv.y, acc[rr][1]);
            acc[rr][2] = fmaf(xv, wv.z, acc[rr][2]);
            acc[rr][3] = fmaf(xv, wv.w, acc[rr][3]);
        }
    }

    float4 bv = *(const float4*)(b + 4 * jg);
#pragma unroll
    for (int rr = 0; rr < 8; rr++) {
        long row = rbase + rb * 8 + rr;
        if (row < totalRows) {
            float4 o;
            o.x = acc[rr][0] + bv.x; o.y = acc[rr][1] + bv.y;
            o.z = acc[rr][2] + bv.z; o.w = acc[rr][3] + bv.w;
            ((float4*)(out + (size_t)row * D))[jg] = o;
        }
    }
}

// ---------------------------------------------------------------------------
extern "C" void kernel_launch(void* const* d_in, const int* in_sizes, int n_in,
                              void* d_out, int out_size, void* d_ws, size_t ws_size,
                              hipStream_t stream)
{
    const float* x     = (const float*)d_in[0];
    const int*   eidx  = (const int*)d_in[1];
    const float* etime = (const float*)d_in[2];
    const float* ntime = (const float*)d_in[3];
    const float* ew    = (const float*)d_in[4];
    const float* W     = (const float*)d_in[5];
    const float* b     = (const float*)d_in[6];
    float* out = (float*)d_out;

    const int T = in_sizes[3];             // 8
    const int E = in_sizes[1] / 2;         // 800000
    const int N = in_sizes[0] / (T * D);   // 50000

    const int* src = eidx;
    const int* dst = eidx + E;

    int* cnt    = (int*)d_ws;
    int* rowptr = cnt + N;
    int* fill   = rowptr + N + 1;
    int* bucket = fill + N;

    hipMemsetAsync(cnt, 0, (size_t)N * sizeof(int), stream);

    hist_kernel<<<(E + 255) / 256, 256, 0, stream>>>(dst, E, cnt);
    scan_kernel<<<1, 1024, 0, stream>>>(cnt, rowptr, fill, N);
    bucket_kernel<<<(E + 255) / 256, 256, 0, stream>>>(dst, E, fill, bucket);

    gather_kernel<<<(N + 3) / 4, 256, 0, stream>>>(x, src, etime, ew, ntime,
                                                   rowptr, bucket, out, N);

    int totalRows = T * N;
    transform_kernel<<<(totalRows + RPB - 1) / RPB, 256, 0, stream>>>(out, W, b, totalRows);
}

// Round 3
// 497.099 us; speedup vs baseline: 1.2256x; 1.2256x over previous
//
#include <hip/hip_runtime.h>
#include <cstdint>
#include <cstddef>

#define TSTEPS 8
#define D 64

static __device__ __forceinline__ unsigned short f2bf(float f) {
    unsigned int u = __float_as_uint(f);
    unsigned int r = (u + 0x7FFFu + ((u >> 16) & 1u)) >> 16;   // RNE
    return (unsigned short)r;
}
static __device__ __forceinline__ float bf2f(unsigned short h) {
    return __uint_as_float(((unsigned int)h) << 16);
}

// ---------------------------------------------------------------------------
// Phase A1: histogram of dst
// ---------------------------------------------------------------------------
__global__ void hist_kernel(const int* __restrict__ dst, int E, int* __restrict__ cnt) {
    int e = blockIdx.x * blockDim.x + threadIdx.x;
    if (e < E) atomicAdd(&cnt[dst[e]], 1);
}

// ---------------------------------------------------------------------------
// Phase A2: hierarchical exclusive scan (block reduce + scan-write)
// Each block covers 1024 elements (256 threads x 4).
// ---------------------------------------------------------------------------
__global__ __launch_bounds__(256) void reduce_kernel(const int* __restrict__ cnt,
                                                     int* __restrict__ sums, int n) {
    __shared__ int red[256];
    int tid = threadIdx.x;
    int base = blockIdx.x * 1024 + tid * 4;
    int tot = 0;
#pragma unroll
    for (int j = 0; j < 4; j++) { int i = base + j; tot += (i < n) ? cnt[i] : 0; }
    red[tid] = tot;
    __syncthreads();
    for (int s = 128; s > 0; s >>= 1) {
        if (tid < s) red[tid] += red[tid + s];
        __syncthreads();
    }
    if (tid == 0) sums[blockIdx.x] = red[0];
}

__global__ __launch_bounds__(256) void scanwrite_kernel(const int* __restrict__ cnt,
                                                        const int* __restrict__ sums,
                                                        int* __restrict__ rowptr,
                                                        int* __restrict__ fill,
                                                        int n, int E) {
    __shared__ int buf[256];
    int tid = threadIdx.x;
    int base = blockIdx.x * 1024 + tid * 4;
    int v[4];
    int tot = 0;
#pragma unroll
    for (int j = 0; j < 4; j++) { int i = base + j; v[j] = (i < n) ? cnt[i] : 0; tot += v[j]; }

    buf[tid] = tot;
    __syncthreads();
    for (int off = 1; off < 256; off <<= 1) {
        int t = (tid >= off) ? buf[tid - off] : 0;
        __syncthreads();
        buf[tid] += t;
        __syncthreads();
    }
    int exclThread = buf[tid] - tot;

    int bp = 0;
    for (int j = 0; j < blockIdx.x; j++) bp += sums[j];   // uniform, scalar loads

    int running = bp + exclThread;
#pragma unroll
    for (int j = 0; j < 4; j++) {
        int i = base + j;
        if (i < n) { rowptr[i] = running; fill[i] = running; running += v[j]; }
    }
    if (blockIdx.x == 0 && tid == 0) rowptr[n] = E;   // sum of degrees == E
}

// ---------------------------------------------------------------------------
// Phase A3: bucket fill with PACKED meta: (src<<4 | t0, weight)
// t0 = #{t : ntime[t] < etime} -> edge active for t in [t0, 8)
// ---------------------------------------------------------------------------
__global__ __launch_bounds__(256) void bucket_kernel(
    const int* __restrict__ src, const int* __restrict__ dst,
    const float* __restrict__ etime, const float* __restrict__ ew,
    const float* __restrict__ ntime, int E,
    int* __restrict__ fill, uint2* __restrict__ meta)
{
    int e = blockIdx.x * blockDim.x + threadIdx.x;
    if (e >= E) return;
    float et = etime[e];
    int t0 = 0;
#pragma unroll
    for (int t = 0; t < TSTEPS; t++) t0 += (ntime[t] < et) ? 1 : 0;
    unsigned int lo = ((unsigned int)src[e] << 4) | (unsigned int)t0;
    uint2 m;
    m.x = lo;
    m.y = __float_as_uint(ew[e]);
    int p = atomicAdd(&fill[dst[e]], 1);
    meta[p] = m;
}

// ---------------------------------------------------------------------------
// Optional: x -> bf16 copy (halves gather read bytes)
// ---------------------------------------------------------------------------
__global__ __launch_bounds__(256) void cvt_kernel(const float* __restrict__ x,
                                                  unsigned short* __restrict__ xb,
                                                  long n4) {
    long i = (long)blockIdx.x * blockDim.x + threadIdx.x;
    if (i >= n4) return;
    float4 v = ((const float4*)x)[i];
    ushort4 u;
    u.x = f2bf(v.x); u.y = f2bf(v.y); u.z = f2bf(v.z); u.w = f2bf(v.w);
    ((ushort4*)xb)[i] = u;
}

// ---------------------------------------------------------------------------
// Phase B (fused): gather + linear.
// One wave per dst node. Lanes split into 4 groups of 16; each group owns one
// edge at a time; lane q within group loads float4/ushort4 of features.
// Cross-group shuffle reduce -> agg row -> LDS broadcast -> row @ W + b.
// ---------------------------------------------------------------------------
template<bool USE_BF16>
__global__ __launch_bounds__(256) void fused_gather_kernel(
    const float* __restrict__ xf, const unsigned short* __restrict__ xb,
    const uint2* __restrict__ meta, const int* __restrict__ rowptr,
    const float* __restrict__ W, const float* __restrict__ b,
    float* __restrict__ out, int N)
{
    __shared__ float Wlds[64 * 64];           // 16 KB
    __shared__ float aggS[4][TSTEPS][64];     // 8 KB

    int tid = threadIdx.x;
#pragma unroll
    for (int i = 0; i < 16; i++) Wlds[tid + i * 256] = W[tid + i * 256];
    __syncthreads();

    int wslot = tid >> 6;
    int lane  = tid & 63;
    int g = lane >> 4;        // edge group 0..3
    int q = lane & 15;        // feature quad within row
    int n = blockIdx.x * 4 + wslot;

    const size_t plane  = (size_t)N * D;       // floats per t-plane
    const size_t plane4 = plane >> 2;          // float4s per t-plane

    float4 acc[TSTEPS];
#pragma unroll
    for (int t = 0; t < TSTEPS; t++) acc[t] = make_float4(0.f, 0.f, 0.f, 0.f);

    if (n < N) {
        int p0 = rowptr[n], p1 = rowptr[n + 1];
        for (int p = p0; p < p1; p += 4) {
            int idx = p + g;
            int s = 0, t0 = TSTEPS;
            float w = 0.f;
            if (idx < p1) {
                uint2 m = meta[idx];
                s  = (int)(m.x >> 4);
                t0 = (int)(m.x & 15u);
                w  = __uint_as_float(m.y);
            }
            if (USE_BF16) {
                const unsigned short* xp = xb + (size_t)s * D + q * 4;
#pragma unroll
                for (int t = 0; t < TSTEPS; t++) {
                    if (t >= t0) {
                        ushort4 u = *reinterpret_cast<const ushort4*>(xp + (size_t)t * plane);
                        acc[t].x = fmaf(bf2f(u.x), w, acc[t].x);
                        acc[t].y = fmaf(bf2f(u.y), w, acc[t].y);
                        acc[t].z = fmaf(bf2f(u.z), w, acc[t].z);
                        acc[t].w = fmaf(bf2f(u.w), w, acc[t].w);
                    }
                }
            } else {
                const float4* xp = reinterpret_cast<const float4*>(xf + (size_t)s * D) + q;
#pragma unroll
                for (int t = 0; t < TSTEPS; t++) {
                    if (t >= t0) {
                        float4 v = xp[(size_t)t * plane4];
                        acc[t].x = fmaf(v.x, w, acc[t].x);
                        acc[t].y = fmaf(v.y, w, acc[t].y);
                        acc[t].z = fmaf(v.z, w, acc[t].z);
                        acc[t].w = fmaf(v.w, w, acc[t].w);
                    }
                }
            }
        }
    }

    // reduce the 4 edge-groups: every lane ends with full sum for its quad
#pragma unroll
    for (int t = 0; t < TSTEPS; t++) {
        acc[t].x += __shfl_xor(acc[t].x, 16); acc[t].y += __shfl_xor(acc[t].y, 16);
        acc[t].z += __shfl_xor(acc[t].z, 16); acc[t].w += __shfl_xor(acc[t].w, 16);
        acc[t].x += __shfl_xor(acc[t].x, 32); acc[t].y += __shfl_xor(acc[t].y, 32);
        acc[t].z += __shfl_xor(acc[t].z, 32); acc[t].w += __shfl_xor(acc[t].w, 32);
    }

    if (lane < 16) {
#pragma unroll
        for (int t = 0; t < TSTEPS; t++)
            *reinterpret_cast<float4*>(&aggS[wslot][t][lane * 4]) = acc[t];
    }
    __syncthreads();   // every wave executes this path (no early returns)

    // transform: out[t][lane] = b[lane] + sum_k agg[t][k] * W[k][lane]
    float o[TSTEPS];
    float bias = b[lane];
#pragma unroll
    for (int t = 0; t < TSTEPS; t++) o[t] = bias;

    for (int kc = 0; kc < 16; kc++) {
        float w0 = Wlds[(4 * kc + 0) * 64 + lane];
        float w1 = Wlds[(4 * kc + 1) * 64 + lane];
        float w2 = Wlds[(4 * kc + 2) * 64 + lane];
        float w3 = Wlds[(4 * kc + 3) * 64 + lane];
#pragma unroll
        for (int t = 0; t < TSTEPS; t++) {
            float4 a = *reinterpret_cast<const float4*>(&aggS[wslot][t][4 * kc]);
            o[t] = fmaf(a.x, w0, fmaf(a.y, w1, fmaf(a.z, w2, fmaf(a.w, w3, o[t]))));
        }
    }

    if (n < N) {
        size_t ob = (size_t)n * D + lane;
#pragma unroll
        for (int t = 0; t < TSTEPS; t++) out[(size_t)t * plane + ob] = o[t];
    }
}

// ---------------------------------------------------------------------------
extern "C" void kernel_launch(void* const* d_in, const int* in_sizes, int n_in,
                              void* d_out, int out_size, void* d_ws, size_t ws_size,
                              hipStream_t stream)
{
    const float* x     = (const float*)d_in[0];
    const int*   eidx  = (const int*)d_in[1];
    const float* etime = (const float*)d_in[2];
    const float* ntime = (const float*)d_in[3];
    const float* ew    = (const float*)d_in[4];
    const float* W     = (const float*)d_in[5];
    const float* b     = (const float*)d_in[6];
    float* out = (float*)d_out;

    const int T = in_sizes[3];             // 8
    const int E = in_sizes[1] / 2;         // 800000
    const int N = in_sizes[0] / (T * D);   // 50000

    const int* src = eidx;
    const int* dst = eidx + E;

    char* base = (char*)d_ws;
    uint2* meta  = (uint2*)base;                     // 8E bytes
    int* cnt     = (int*)(base + 8ll * E);
    int* rowptr  = cnt + N;
    int* fill    = rowptr + N + 1;
    int* sums    = fill + N;
    size_t off = 8ll * E + 4ll * (3ll * N + 1 + 64);
    off = (off + 15) & ~(size_t)15;
    unsigned short* xb = (unsigned short*)(base + off);
    size_t need = off + 2ll * T * N * D;
    bool useBf16 = (ws_size >= need);

    hipMemsetAsync(cnt, 0, (size_t)N * sizeof(int), stream);

    hist_kernel<<<(E + 255) / 256, 256, 0, stream>>>(dst, E, cnt);

    int nb = (N + 1023) / 1024;
    reduce_kernel<<<nb, 256, 0, stream>>>(cnt, sums, N);
    scanwrite_kernel<<<nb, 256, 0, stream>>>(cnt, sums, rowptr, fill, N, E);

    bucket_kernel<<<(E + 255) / 256, 256, 0, stream>>>(src, dst, etime, ew, ntime,
                                                       E, fill, meta);

    if (useBf16) {
        long n4 = (long)T * N * D / 4;
        cvt_kernel<<<(int)((n4 + 255) / 256), 256, 0, stream>>>(x, xb, n4);
        fused_gather_kernel<true><<<(N + 3) / 4, 256, 0, stream>>>(
            x, xb, meta, rowptr, W, b, out, N);
    } else {
        fused_gather_kernel<false><<<(N + 3) / 4, 256, 0, stream>>>(
            x, xb, meta, rowptr, W, b, out, N);
    }
}